// Round 1
// baseline (792.346 us; speedup 1.0000x reference)
//
#include <hip/hip_runtime.h>

#define NUM_VOXELS     1000000
#define N_POINTS       1500000
#define TOTAL_PROP_PTS 1000000
#define NUM_PROPOSALS  2048
#define IN_CH          134
#define M_OUT          16

// ---------------------------------------------------------------------------
// K1: feats = relu(voxel_feats @ W)
//   A: [NUM_VOXELS][134] f32 (row 536 B), W: [134][16] f32, feats: [NUM_VOXELS][16]
// Mapping: block = 256 threads = 4 waves; each wave owns 64 voxels and a
// wave-private LDS chunk [64 rows][65 cols] (pad-65 -> bank stride 1 ->
// <=2-way aliasing everywhere, free). K staged in chunks of 64 (+6 tail).
// W is read at wave-uniform addresses -> scalar loads, FMA with SGPR operand.
// No __syncthreads needed (LDS strictly wave-private).
// ---------------------------------------------------------------------------
__global__ __launch_bounds__(256, 2) void k_gemm_relu(
    const float* __restrict__ A, const float* __restrict__ W,
    float* __restrict__ feats)
{
    __shared__ float lds[4][64 * 65];
    const int wave = threadIdx.x >> 6;
    const int lane = threadIdx.x & 63;
    const int v0   = blockIdx.x * 256 + wave * 64;   // wave's first voxel
    if (v0 >= NUM_VOXELS) return;                    // NUM_VOXELS % 64 == 0

    float* chunk = lds[wave];
    float acc[M_OUT];
#pragma unroll
    for (int c = 0; c < M_OUT; ++c) acc[c] = 0.f;

    for (int kc = 0; kc < IN_CH; kc += 64) {
        const int KC = (IN_CH - kc) >= 64 ? 64 : (IN_CH - kc);
        if (KC == 64) {
            // staging: iteration j covers rows 2j (lanes 0..31) and 2j+1 (32..63),
            // each lane loads a float2 -> fully coalesced, 8B-aligned.
            const int half = lane >> 5;
            const int c2   = (lane & 31) * 2;
#pragma unroll 4
            for (int j = 0; j < 32; ++j) {
                const int row = j * 2 + half;
                const float2 val = *(const float2*)(A + (size_t)(v0 + row) * IN_CH + kc + c2);
                chunk[row * 65 + c2]     = val.x;
                chunk[row * 65 + c2 + 1] = val.y;
            }
        } else {
            // tail KC = 6: 64*6 = 384 elements, e = j*64 + lane
#pragma unroll
            for (int j = 0; j < 6; ++j) {
                const int e   = j * 64 + lane;
                const int row = e / 6;
                const int col = e - row * 6;
                chunk[row * 65 + col] = A[(size_t)(v0 + row) * IN_CH + kc + col];
            }
        }
        // compute: lane = voxel; per kk one LDS read (bank-free) + 16 FMAs
        // with wave-uniform W (scalar loads).
        const float* wbase = W + kc * M_OUT;
        for (int kk = 0; kk < KC; ++kk) {
            const float a = chunk[lane * 65 + kk];
            const float* wr = wbase + kk * M_OUT;
#pragma unroll
            for (int c = 0; c < M_OUT; ++c) acc[c] = fmaf(a, wr[c], acc[c]);
        }
    }

    // relu + store 64 B per voxel
    float4* orow = (float4*)(feats + (size_t)(v0 + lane) * M_OUT);
#pragma unroll
    for (int q = 0; q < 4; ++q) {
        float4 o;
        o.x = fmaxf(acc[q * 4 + 0], 0.f);
        o.y = fmaxf(acc[q * 4 + 1], 0.f);
        o.z = fmaxf(acc[q * 4 + 2], 0.f);
        o.w = fmaxf(acc[q * 4 + 3], 0.f);
        orow[q] = o;
    }
}

// ---------------------------------------------------------------------------
// K2: per-proposal segmented mean + batchId + objectness.
// Segments are contiguous ranges [off[s], off[s+1]) of t -- one block per
// proposal, thread-per-point (256 gather chains in flight hides the
// idx -> p2v -> feats dependent-load latency), then shfl + LDS reduction.
// out layout (all f32): [P*16 means][P batchId][P ones]
// ---------------------------------------------------------------------------
__global__ __launch_bounds__(256) void k_propmean(
    const float* __restrict__ feats,
    const int*   __restrict__ p2v,       // [N_POINTS]
    const int*   __restrict__ prop_idx,  // [T][2], col 1 = point index
    const int*   __restrict__ offsets,   // [P+1]
    const int*   __restrict__ locs,      // [N_POINTS][4], col 0 = batch id
    float*       __restrict__ out)
{
    const int s   = blockIdx.x;
    const int tid = threadIdx.x;
    const int t0  = offsets[s];
    const int t1  = offsets[s + 1];

    float acc[M_OUT];
#pragma unroll
    for (int c = 0; c < M_OUT; ++c) acc[c] = 0.f;

    for (int t = t0 + tid; t < t1; t += 256) {
        const int p = prop_idx[2 * t + 1];
        const int v = p2v[p];
        const float4* fp = (const float4*)(feats + (size_t)v * M_OUT);
        const float4 f0 = fp[0], f1 = fp[1], f2 = fp[2], f3 = fp[3];
        acc[0]  += f0.x; acc[1]  += f0.y; acc[2]  += f0.z; acc[3]  += f0.w;
        acc[4]  += f1.x; acc[5]  += f1.y; acc[6]  += f1.z; acc[7]  += f1.w;
        acc[8]  += f2.x; acc[9]  += f2.y; acc[10] += f2.z; acc[11] += f2.w;
        acc[12] += f3.x; acc[13] += f3.y; acc[14] += f3.z; acc[15] += f3.w;
    }

    // wave-level reduction (width 64)
#pragma unroll
    for (int c = 0; c < M_OUT; ++c) {
#pragma unroll
        for (int off = 32; off > 0; off >>= 1)
            acc[c] += __shfl_down(acc[c], off, 64);
    }

    __shared__ float red[4][M_OUT];
    const int lane = tid & 63, wv = tid >> 6;
    if (lane == 0) {
#pragma unroll
        for (int c = 0; c < M_OUT; ++c) red[wv][c] = acc[c];
    }
    __syncthreads();

    if (tid < M_OUT) {
        const float sum = red[0][tid] + red[1][tid] + red[2][tid] + red[3][tid];
        const float cnt = (float)(t1 - t0);
        out[s * M_OUT + tid] = sum / fmaxf(cnt, 1.f);
    }
    if (tid == 0) {
        // offsets[s] < T for s < P, so this index is always valid
        const int p = prop_idx[2 * t0 + 1];
        out[NUM_PROPOSALS * M_OUT + s]                 = (float)locs[4 * p];
        out[NUM_PROPOSALS * M_OUT + NUM_PROPOSALS + s] = 1.0f;
    }
}

// ---------------------------------------------------------------------------
extern "C" void kernel_launch(void* const* d_in, const int* in_sizes, int n_in,
                              void* d_out, int out_size, void* d_ws, size_t ws_size,
                              hipStream_t stream)
{
    const float* A    = (const float*)d_in[0];   // voxel_feats [1M][134]
    const float* W    = (const float*)d_in[1];   // [134][16]
    const int*   p2v  = (const int*)  d_in[2];   // [1.5M]
    const int*   pidx = (const int*)  d_in[3];   // [1M][2]
    const int*   offs = (const int*)  d_in[4];   // [2049]
    const int*   locs = (const int*)  d_in[5];   // [1.5M][4]
    float*       out  = (float*)      d_out;     // 36864 f32
    float*       feats = (float*)     d_ws;      // 64 MB scratch

    k_gemm_relu<<<(NUM_VOXELS + 255) / 256, 256, 0, stream>>>(A, W, feats);
    k_propmean<<<NUM_PROPOSALS, 256, 0, stream>>>(feats, p2v, pidx, offs, locs, out);
}